// Round 7
// baseline (244.721 us; speedup 1.0000x reference)
//
#include <hip/hip_runtime.h>
#include <math.h>

#define B 8
#define S 1024
#define D 1024
#define F 3584

#define KSV 64     // split-K chunks for 1024x1024 matvecs (16 rows each)
#define CHV 16
#define KS5 32     // gate/up split-K chunks (32 rows each) -> 448 blocks
#define CH5 32
#define KS6 224    // down split-K chunks (16 rows each)    -> 448 blocks
#define CH6 16

typedef float f4v __attribute__((ext_vector_type(4)));
#define LD4(p) (*(const f4v*)(p))

#define FMA4(A, s, W) { (A).x += (s)*(W).x; (A).y += (s)*(W).y; (A).z += (s)*(W).z; (A).w += (s)*(W).w; }

// 8-row FMA step for one token-batch bb against weight regs w0..w7
#define BB8(bb, ACC, XS, CH, koff) { \
  f4v xa = LD4((XS) + (bb)*(CH) + (koff)); \
  f4v xb = LD4((XS) + (bb)*(CH) + (koff) + 4); \
  FMA4(ACC, xa.x, w0); FMA4(ACC, xa.y, w1); FMA4(ACC, xa.z, w2); FMA4(ACC, xa.w, w3); \
  FMA4(ACC, xb.x, w4); FMA4(ACC, xb.y, w5); FMA4(ACC, xb.z, w6); FMA4(ACC, xb.w, w7); }

#define ALL8(XS, CH, koff) \
  BB8(0, acc0, XS, CH, koff) BB8(1, acc1, XS, CH, koff) \
  BB8(2, acc2, XS, CH, koff) BB8(3, acc3, XS, CH, koff) \
  BB8(4, acc4, XS, CH, koff) BB8(5, acc5, XS, CH, koff) \
  BB8(6, acc6, XS, CH, koff) BB8(7, acc7, XS, CH, koff)

// ---------------- block-wide sum for 256-thread blocks ----------------
__device__ __forceinline__ float block_sum256(float v, volatile float* buf) {
  #pragma unroll
  for (int o = 32; o; o >>= 1) v += __shfl_down(v, o);   // wave64 reduce
  __syncthreads();
  if ((threadIdx.x & 63) == 0) buf[threadIdx.x >> 6] = v;
  __syncthreads();
  return buf[0] + buf[1] + buf[2] + buf[3];
}

// Weight load: NT=1 -> nontemporal (cold streams we don't want resident),
// NT=0 -> plain (expected LLC hit after prefetch).
template<int NT>
__device__ __forceinline__ f4v wld(const f4v* p) {
  if constexpr (NT) return __builtin_nontemporal_load(p);
  else return *p;
}

// LLC prefetch: stream a weight array with plain (allocating) loads.
// Runs on otherwise-idle blocks of latency-bound kernels; absorbs the
// poison-fill dirty-eviction writebacks so consumer kernels hit LLC.
__device__ __forceinline__ void prefetch_llc(const float* __restrict__ w,
                                             int nf4, int pid, int nblk,
                                             int tid, float* __restrict__ dummy) {
  const f4v* p = (const f4v*)w;
  int stride = nblk * 256;
  f4v acc = {0.f, 0.f, 0.f, 0.f};
  for (int i = pid * 256 + tid; i < nf4; i += stride) acc += p[i];
  float t = acc.x + acc.y + acc.z + acc.w;
  if (t > 1e30f) dummy[0] = t;   // opaque: keeps loads live, never fires
}

// 16-row x 1024-col x 8-token matvec step.
// Optional per-token store predicate: ssel[bb]==e (ssel=nullptr -> always).
template<int NT>
__device__ __forceinline__ void mv16(const float* __restrict__ W, int j,
                                     float* __restrict__ Pout,
                                     const float* xs,
                                     const int* ssel, int e) {
  const f4v* Wp = (const f4v*)(W + j);
  const int st = D / 4;
  f4v acc0 = {0,0,0,0}, acc1 = {0,0,0,0}, acc2 = {0,0,0,0}, acc3 = {0,0,0,0};
  f4v acc4 = {0,0,0,0}, acc5 = {0,0,0,0}, acc6 = {0,0,0,0}, acc7 = {0,0,0,0};
  f4v w0 = wld<NT>(Wp+0*st), w1 = wld<NT>(Wp+1*st), w2 = wld<NT>(Wp+2*st), w3 = wld<NT>(Wp+3*st);
  f4v w4 = wld<NT>(Wp+4*st), w5 = wld<NT>(Wp+5*st), w6 = wld<NT>(Wp+6*st), w7 = wld<NT>(Wp+7*st);
  f4v v0 = wld<NT>(Wp+8*st), v1 = wld<NT>(Wp+9*st), v2 = wld<NT>(Wp+10*st), v3 = wld<NT>(Wp+11*st);
  f4v v4 = wld<NT>(Wp+12*st), v5 = wld<NT>(Wp+13*st), v6 = wld<NT>(Wp+14*st), v7 = wld<NT>(Wp+15*st);
  ALL8(xs, CHV, 0);
  w0 = v0; w1 = v1; w2 = v2; w3 = v3; w4 = v4; w5 = v5; w6 = v6; w7 = v7;
  ALL8(xs, CHV, 8);
  #define MV_ST(bb, ACC) \
    if (!ssel || ssel[bb] == e) *(f4v*)(Pout + (bb)*(size_t)D + j) = ACC;
  MV_ST(0, acc0) MV_ST(1, acc1) MV_ST(2, acc2) MV_ST(3, acc3)
  MV_ST(4, acc4) MV_ST(5, acc5) MV_ST(6, acc6) MV_ST(7, acc7)
  #undef MV_ST
}

#define NF4_GATE (2 * D * F / 4)   // 1835008 float4s (both experts)

// K1: rmsnorm-1 folded into V-matvec (blocks 0..63); blocks 64..255 prefetch
// gate_w into LLC.
__global__ __launch_bounds__(256, 2) void k_mvp_v(const float* __restrict__ hs,
                                                  const float* __restrict__ ln1w,
                                                  const float* __restrict__ vw,
                                                  const float* __restrict__ gw,
                                                  float* __restrict__ Vp,
                                                  float* __restrict__ dummy) {
  __shared__ float xs[8 * CHV];
  __shared__ float scsh[8];
  int tid = threadIdx.x;
  int bid = blockIdx.x;
  if (bid >= KSV) {
    prefetch_llc(gw, NF4_GATE, bid - KSV, 256 - KSV, tid, dummy);
    return;
  }
  int w = tid >> 6, lane = tid & 63;
  #pragma unroll
  for (int b2 = 0; b2 < 2; b2++) {
    int b = w * 2 + b2;
    const f4v* hp = (const f4v*)(hs + (size_t)b * S * D);
    float ss = 0.f;
    #pragma unroll
    for (int t = 0; t < 4; t++) {
      f4v v = hp[lane * 4 + t];
      ss += v.x*v.x + v.y*v.y + v.z*v.z + v.w*v.w;
    }
    #pragma unroll
    for (int o = 32; o; o >>= 1) ss += __shfl_down(ss, o);
    if (lane == 0) scsh[b] = rsqrtf(ss * (1.f / (float)D) + 1e-6f);
  }
  __syncthreads();
  int i0 = bid * CHV;
  if (tid < 128) {
    int bb = tid >> 4, ii = tid & 15;
    xs[tid] = hs[(size_t)bb * S * D + i0 + ii] * scsh[bb] * ln1w[i0 + ii];
  }
  __syncthreads();
  mv16<1>(vw + (size_t)i0 * D, tid * 4, Vp + (size_t)bid * 8 * D, xs, 0, 0);
}

// K2: reduce Vp slice -> LDS, then O-projection partials (blocks 0..63);
// blocks 64..255 prefetch up_w.
__global__ __launch_bounds__(256, 2) void k_ored(const float* __restrict__ Vp,
                                                 const float* __restrict__ ow,
                                                 const float* __restrict__ uw,
                                                 float* __restrict__ Op,
                                                 float* __restrict__ dummy) {
  __shared__ float xs[8 * CHV];
  int tid = threadIdx.x;
  int bid = blockIdx.x;
  if (bid >= KSV) {
    prefetch_llc(uw, NF4_GATE, bid - KSV, 256 - KSV, tid, dummy);
    return;
  }
  int i0 = bid * CHV;
  if (tid < 128) {
    int bb = tid >> 4, ii = tid & 15;
    float s = 0.f;
    #pragma unroll 16
    for (int p = 0; p < KSV; p++) s += Vp[((size_t)p * 8 + bb) * D + i0 + ii];
    xs[bb * CHV + ii] = s;
  }
  __syncthreads();
  mv16<1>(ow + (size_t)i0 * D, tid * 4, Op + (size_t)bid * 8 * D, xs, 0, 0);
}

// K3: xr/h2/router (blocks 0..7); blocks 8..255 prefetch down_w.
__global__ void k_mid(const float* __restrict__ hs, const float* __restrict__ Op,
                      const float* __restrict__ ln2, const float* __restrict__ rw,
                      const float* __restrict__ dwp,
                      float* __restrict__ xr, float* __restrict__ h2,
                      float* __restrict__ topw, int* __restrict__ sel,
                      float* __restrict__ dummy) {
  __shared__ float buf[4];
  int b = blockIdx.x;
  if (b >= 8) {
    prefetch_llc(dwp, NF4_GATE, b - 8, 248, threadIdx.x, dummy);
    return;
  }
  int idx = threadIdx.x * 4;
  f4v x = LD4(hs + (size_t)b * S * D + idx);
  #pragma unroll 16
  for (int p = 0; p < KSV; p++) {
    f4v v = LD4(Op + ((size_t)p * 8 + b) * D + idx);
    x.x += v.x; x.y += v.y; x.z += v.z; x.w += v.w;
  }
  *(f4v*)(xr + b * D + idx) = x;
  float ss = x.x*x.x + x.y*x.y + x.z*x.z + x.w*x.w;
  float tot = block_sum256(ss, buf);
  float sc = rsqrtf(tot * (1.f / (float)D) + 1e-6f);
  f4v wv = LD4(ln2 + idx);
  f4v h;
  h.x = x.x*sc*wv.x; h.y = x.y*sc*wv.y; h.z = x.z*sc*wv.z; h.w = x.w*sc*wv.w;
  *(f4v*)(h2 + b * D + idx) = h;
  float r0 = h.x * rw[idx * 2]     + h.y * rw[(idx + 1) * 2] +
             h.z * rw[(idx + 2) * 2] + h.w * rw[(idx + 3) * 2];
  float r1 = h.x * rw[idx * 2 + 1]     + h.y * rw[(idx + 1) * 2 + 1] +
             h.z * rw[(idx + 2) * 2 + 1] + h.w * rw[(idx + 3) * 2 + 1];
  r0 = block_sum256(r0, buf);
  r1 = block_sum256(r1, buf);
  if (threadIdx.x == 0) {
    float m = fmaxf(r0, r1);
    float e0 = __expf(r0 - m), e1 = __expf(r1 - m);
    float inv = 1.f / (e0 + e1);
    float p0 = e0 * inv, p1 = e1 * inv;
    topw[b] = fmaxf(p0, p1);
    sel[b] = (p1 > p0) ? 1 : 0;
  }
}

// K4: gate/up split-K partials; weights expected LLC-resident (plain loads).
// grid=(14, KS5) = 448 blocks. Stores only tokens routed to this expert.
__global__ __launch_bounds__(256, 2) void k_gateup(const float* __restrict__ h2,
                                                   const float* __restrict__ gw,
                                                   const float* __restrict__ uw,
                                                   const int* __restrict__ sel,
                                                   float* __restrict__ Pgu) {
  __shared__ float xs[8 * CH5];
  __shared__ int ssel[8];
  int tid = threadIdx.x;
  int kc = blockIdx.y, colt = blockIdx.x;
  int i0 = kc * CH5;
  { int bb = tid >> 5, r = tid & 31;
    xs[tid] = h2[bb * D + i0 + r]; }
  if (tid < 8) ssel[tid] = sel[tid];
  __syncthreads();
  int c = colt * 1024 + tid * 4;     // flattened col over 4 matrices (4*F)
  int m = c / F;
  int j = c - m * F;
  const float* base = (m < 2 ? gw : uw) + (size_t)(m & 1) * D * F;
  const f4v* Wp = (const f4v*)(base + (size_t)i0 * F + j);
  const int st = F / 4;
  f4v acc0 = {0,0,0,0}, acc1 = {0,0,0,0}, acc2 = {0,0,0,0}, acc3 = {0,0,0,0};
  f4v acc4 = {0,0,0,0}, acc5 = {0,0,0,0}, acc6 = {0,0,0,0}, acc7 = {0,0,0,0};
  f4v w0 = Wp[0*st], w1 = Wp[1*st], w2 = Wp[2*st], w3 = Wp[3*st];
  f4v w4 = Wp[4*st], w5 = Wp[5*st], w6 = Wp[6*st], w7 = Wp[7*st];
  Wp += 8 * st;
  #pragma unroll
  for (int t = 0; t < CH5 / 8 - 1; t++) {
    f4v n0 = Wp[0*st], n1 = Wp[1*st], n2 = Wp[2*st], n3 = Wp[3*st];
    f4v n4 = Wp[4*st], n5 = Wp[5*st], n6 = Wp[6*st], n7 = Wp[7*st];
    Wp += 8 * st;
    ALL8(xs, CH5, t * 8);
    w0 = n0; w1 = n1; w2 = n2; w3 = n3; w4 = n4; w5 = n5; w6 = n6; w7 = n7;
  }
  ALL8(xs, CH5, CH5 - 8);
  int me = m & 1;
  #define GU_ST(bb, ACC) \
    if (ssel[bb] == me) \
      *(f4v*)(Pgu + (((size_t)kc * 4 + m) * 8 + (bb)) * F + j) = ACC;
  GU_ST(0, acc0) GU_ST(1, acc1) GU_ST(2, acc2) GU_ST(3, acc3)
  GU_ST(4, acc4) GU_ST(5, acc5) GU_ST(6, acc6) GU_ST(7, acc7)
  #undef GU_ST
}

// K5: silu-reduce Pgu slice -> LDS (selected tokens only), then down partials
// (weights LLC-resident, plain loads). grid = 2*KS6 = 448.
__global__ __launch_bounds__(256, 2) void k_down(const float* __restrict__ Pgu,
                                                 const float* __restrict__ dw,
                                                 const int* __restrict__ sel,
                                                 float* __restrict__ Dp) {
  __shared__ float xs[8 * CH6];
  __shared__ int ssel[8];
  int tid = threadIdx.x;
  int e = blockIdx.x & 1, ch = blockIdx.x >> 1, i0 = ch * CH6;
  if (tid < 8) ssel[tid] = sel[tid];
  __syncthreads();
  if (tid < 128) {
    int bb = tid >> 4, ii = tid & 15;
    float r = 0.f;
    if (ssel[bb] == e) {
      float ga = 0.f, ua = 0.f;
      #pragma unroll
      for (int kc = 0; kc < KS5; kc++) {
        ga += Pgu[(((size_t)kc * 4 + e)     * 8 + bb) * F + i0 + ii];
        ua += Pgu[(((size_t)kc * 4 + 2 + e) * 8 + bb) * F + i0 + ii];
      }
      r = (ga / (1.f + __expf(-ga))) * ua;
    }
    xs[bb * CH6 + ii] = r;
  }
  __syncthreads();
  mv16<0>(dw + (size_t)e * F * D + (size_t)i0 * D, tid * 4,
          Dp + (((size_t)ch * 2 + e) * 8) * D, xs, ssel, e);
}

// K6: x2 = xr + top_w * sum_p Dp[p][sel]; final rmsnorm; logits. grid=8.
__global__ void k_final(const float* __restrict__ xr, const float* __restrict__ Dp,
                        const float* __restrict__ topw, const int* __restrict__ sel,
                        const float* __restrict__ flw, const float* __restrict__ sw,
                        float* __restrict__ out) {
  __shared__ float buf[4];
  int b = blockIdx.x;
  int e = sel[b];
  float tw = topw[b];
  int idx = threadIdx.x * 4;
  f4v y = {0,0,0,0};
  #pragma unroll 16
  for (int p = 0; p < KS6; p++) {
    f4v v = LD4(Dp + (((size_t)p * 2 + e) * 8 + b) * D + idx);
    y.x += v.x; y.y += v.y; y.z += v.z; y.w += v.w;
  }
  f4v x = LD4(xr + b * D + idx);
  x.x += tw * y.x; x.y += tw * y.y; x.z += tw * y.z; x.w += tw * y.w;
  float ss = x.x*x.x + x.y*x.y + x.z*x.z + x.w*x.w;
  float tot = block_sum256(ss, buf);
  float sc = rsqrtf(tot * (1.f / (float)D) + 1e-6f);
  f4v wv = LD4(flw + idx);
  float n0 = x.x*sc*wv.x, n1 = x.y*sc*wv.y, n2 = x.z*sc*wv.z, n3 = x.w*sc*wv.w;
  float l0 = n0 * sw[idx * 2]     + n1 * sw[(idx + 1) * 2] +
             n2 * sw[(idx + 2) * 2] + n3 * sw[(idx + 3) * 2];
  float l1 = n0 * sw[idx * 2 + 1]     + n1 * sw[(idx + 1) * 2 + 1] +
             n2 * sw[(idx + 2) * 2 + 1] + n3 * sw[(idx + 3) * 2 + 1];
  l0 = block_sum256(l0, buf);
  l1 = block_sum256(l1, buf);
  if (threadIdx.x == 0) { out[b * 2 + 0] = l0; out[b * 2 + 1] = l1; }
}

extern "C" void kernel_launch(void* const* d_in, const int* in_sizes, int n_in,
                              void* d_out, int out_size, void* d_ws, size_t ws_size,
                              hipStream_t stream) {
  const float* hs  = (const float*)d_in[0];
  const float* ln1 = (const float*)d_in[1];
  // d_in[2]=q_w, d_in[3]=k_w: dead — token-0 causal attention only needs V.
  const float* vw  = (const float*)d_in[4];
  const float* ow  = (const float*)d_in[5];
  const float* ln2 = (const float*)d_in[6];
  const float* rw  = (const float*)d_in[7];
  const float* gw  = (const float*)d_in[8];
  const float* uw  = (const float*)d_in[9];
  const float* dw  = (const float*)d_in[10];
  const float* flw = (const float*)d_in[11];
  const float* sw  = (const float*)d_in[12];

  float* ws = (float*)d_ws;
  float* Vp   = ws;                     // 524288  (KSV*8*D)
  float* Op   = ws + 524288;            // 524288
  float* xr   = ws + 1048576;           // 8192
  float* h2   = ws + 1056768;           // 8192
  float* tw8  = ws + 1064960;           // 8
  int*   sel8 = (int*)(ws + 1064968);   // 8 (+pad to 128B line)
  float* Pgu  = ws + 1064992;           // KS5*4*8*F = 3670016 (128B-aligned)
  float* Dp   = ws + 4735008;           // KS6*2*8*D = 3670016 (128B-aligned)
  float* dummy = ws + 8405024;          // anti-DCE sink for prefetch
  // no atomics, no barrier -> no zero-init; every read cell is written first.

  k_mvp_v<<<256, 256, 0, stream>>>(hs, ln1, vw, gw, Vp, dummy);
  k_ored<<<256, 256, 0, stream>>>(Vp, ow, uw, Op, dummy);
  k_mid<<<256, 256, 0, stream>>>(hs, Op, ln2, rw, dw, xr, h2, tw8, sel8, dummy);
  k_gateup<<<dim3(14, KS5), 256, 0, stream>>>(h2, gw, uw, sel8, Pgu);
  k_down<<<2 * KS6, 256, 0, stream>>>(Pgu, dw, sel8, Dp);
  k_final<<<8, 256, 0, stream>>>(xr, Dp, tw8, sel8, flw, sw, (float*)d_out);
}

// Round 8
// 211.381 us; speedup vs baseline: 1.1577x; 1.1577x over previous
//
#include <hip/hip_runtime.h>
#include <math.h>

#define B 8
#define S 1024
#define D 1024
#define F 3584

#define KSV 64     // split-K chunks for 1024x1024 matvecs (16 rows each)
#define CHV 16
#define KS5 32     // gate/up split-K chunks (32 rows each) -> 448 blocks
#define CH5 32
#define KS6 224    // down split-K chunks (16 rows each)    -> 448 blocks
#define CH6 16

typedef float f4v __attribute__((ext_vector_type(4)));
#define LD4(p) (*(const f4v*)(p))

#define FMA4(A, s, W) { (A).x += (s)*(W).x; (A).y += (s)*(W).y; (A).z += (s)*(W).z; (A).w += (s)*(W).w; }

// 8-row FMA step for one token-batch bb against weight regs w0..w7
#define BB8(bb, ACC, XS, CH, koff) { \
  f4v xa = LD4((XS) + (bb)*(CH) + (koff)); \
  f4v xb = LD4((XS) + (bb)*(CH) + (koff) + 4); \
  FMA4(ACC, xa.x, w0); FMA4(ACC, xa.y, w1); FMA4(ACC, xa.z, w2); FMA4(ACC, xa.w, w3); \
  FMA4(ACC, xb.x, w4); FMA4(ACC, xb.y, w5); FMA4(ACC, xb.z, w6); FMA4(ACC, xb.w, w7); }

#define ALL8(XS, CH, koff) \
  BB8(0, acc0, XS, CH, koff) BB8(1, acc1, XS, CH, koff) \
  BB8(2, acc2, XS, CH, koff) BB8(3, acc3, XS, CH, koff) \
  BB8(4, acc4, XS, CH, koff) BB8(5, acc5, XS, CH, koff) \
  BB8(6, acc6, XS, CH, koff) BB8(7, acc7, XS, CH, koff)

// ---------------- block-wide sum for 256-thread blocks ----------------
__device__ __forceinline__ float block_sum256(float v, volatile float* buf) {
  #pragma unroll
  for (int o = 32; o; o >>= 1) v += __shfl_down(v, o);   // wave64 reduce
  __syncthreads();
  if ((threadIdx.x & 63) == 0) buf[threadIdx.x >> 6] = v;
  __syncthreads();
  return buf[0] + buf[1] + buf[2] + buf[3];
}

// Weight load: NT=1 -> nontemporal (single-use streams), NT=0 -> plain.
template<int NT>
__device__ __forceinline__ f4v wld(const f4v* p) {
  if constexpr (NT) return __builtin_nontemporal_load(p);
  else return *p;
}

// 16-row x 1024-col x 8-token matvec step.
// Optional per-token store predicate: ssel[bb]==e (ssel=nullptr -> always).
template<int NT>
__device__ __forceinline__ void mv16(const float* __restrict__ W, int j,
                                     float* __restrict__ Pout,
                                     const float* xs,
                                     const int* ssel, int e) {
  const f4v* Wp = (const f4v*)(W + j);
  const int st = D / 4;
  f4v acc0 = {0,0,0,0}, acc1 = {0,0,0,0}, acc2 = {0,0,0,0}, acc3 = {0,0,0,0};
  f4v acc4 = {0,0,0,0}, acc5 = {0,0,0,0}, acc6 = {0,0,0,0}, acc7 = {0,0,0,0};
  f4v w0 = wld<NT>(Wp+0*st), w1 = wld<NT>(Wp+1*st), w2 = wld<NT>(Wp+2*st), w3 = wld<NT>(Wp+3*st);
  f4v w4 = wld<NT>(Wp+4*st), w5 = wld<NT>(Wp+5*st), w6 = wld<NT>(Wp+6*st), w7 = wld<NT>(Wp+7*st);
  f4v v0 = wld<NT>(Wp+8*st), v1 = wld<NT>(Wp+9*st), v2 = wld<NT>(Wp+10*st), v3 = wld<NT>(Wp+11*st);
  f4v v4 = wld<NT>(Wp+12*st), v5 = wld<NT>(Wp+13*st), v6 = wld<NT>(Wp+14*st), v7 = wld<NT>(Wp+15*st);
  ALL8(xs, CHV, 0);
  w0 = v0; w1 = v1; w2 = v2; w3 = v3; w4 = v4; w5 = v5; w6 = v6; w7 = v7;
  ALL8(xs, CHV, 8);
  #define MV_ST(bb, ACC) \
    if (!ssel || ssel[bb] == e) *(f4v*)(Pout + (bb)*(size_t)D + j) = ACC;
  MV_ST(0, acc0) MV_ST(1, acc1) MV_ST(2, acc2) MV_ST(3, acc3)
  MV_ST(4, acc4) MV_ST(5, acc5) MV_ST(6, acc6) MV_ST(7, acc7)
  #undef MV_ST
}

// K1: rmsnorm-1 folded into V-matvec. 64 blocks; each redundantly computes the
// 8 per-token rms scales (each wave handles 2 tokens), stages its 16-row slice
// of h1 = hs*sc*ln1 into LDS, runs the matvec.
__global__ __launch_bounds__(256, 2) void k_mvp_v(const float* __restrict__ hs,
                                                  const float* __restrict__ ln1w,
                                                  const float* __restrict__ vw,
                                                  float* __restrict__ Vp) {
  __shared__ float xs[8 * CHV];
  __shared__ float scsh[8];
  int tid = threadIdx.x;
  int bid = blockIdx.x;
  int w = tid >> 6, lane = tid & 63;
  #pragma unroll
  for (int b2 = 0; b2 < 2; b2++) {
    int b = w * 2 + b2;
    const f4v* hp = (const f4v*)(hs + (size_t)b * S * D);
    float ss = 0.f;
    #pragma unroll
    for (int t = 0; t < 4; t++) {
      f4v v = hp[lane * 4 + t];
      ss += v.x*v.x + v.y*v.y + v.z*v.z + v.w*v.w;
    }
    #pragma unroll
    for (int o = 32; o; o >>= 1) ss += __shfl_down(ss, o);
    if (lane == 0) scsh[b] = rsqrtf(ss * (1.f / (float)D) + 1e-6f);
  }
  __syncthreads();
  int i0 = bid * CHV;
  if (tid < 128) {
    int bb = tid >> 4, ii = tid & 15;
    xs[tid] = hs[(size_t)bb * S * D + i0 + ii] * scsh[bb] * ln1w[i0 + ii];
  }
  __syncthreads();
  mv16<1>(vw + (size_t)i0 * D, tid * 4, Vp + (size_t)bid * 8 * D, xs, 0, 0);
}

// K2: reduce Vp slice -> LDS, then O-projection partials. 64 blocks.
__global__ __launch_bounds__(256, 2) void k_ored(const float* __restrict__ Vp,
                                                 const float* __restrict__ ow,
                                                 float* __restrict__ Op) {
  __shared__ float xs[8 * CHV];
  int tid = threadIdx.x;
  int bid = blockIdx.x;
  int i0 = bid * CHV;
  if (tid < 128) {
    int bb = tid >> 4, ii = tid & 15;
    float s = 0.f;
    #pragma unroll 16
    for (int p = 0; p < KSV; p++) s += Vp[((size_t)p * 8 + bb) * D + i0 + ii];
    xs[bb * CHV + ii] = s;
  }
  __syncthreads();
  mv16<1>(ow + (size_t)i0 * D, tid * 4, Op + (size_t)bid * 8 * D, xs, 0, 0);
}

// K3: xr = hs + attn_out; h2 = rmsnorm(xr, ln2); router top-1. grid=8.
__global__ void k_mid(const float* __restrict__ hs, const float* __restrict__ Op,
                      const float* __restrict__ ln2, const float* __restrict__ rw,
                      float* __restrict__ xr, float* __restrict__ h2,
                      float* __restrict__ topw, int* __restrict__ sel) {
  __shared__ float buf[4];
  int b = blockIdx.x;
  int idx = threadIdx.x * 4;
  f4v x = LD4(hs + (size_t)b * S * D + idx);
  #pragma unroll 16
  for (int p = 0; p < KSV; p++) {
    f4v v = LD4(Op + ((size_t)p * 8 + b) * D + idx);
    x.x += v.x; x.y += v.y; x.z += v.z; x.w += v.w;
  }
  *(f4v*)(xr + b * D + idx) = x;
  float ss = x.x*x.x + x.y*x.y + x.z*x.z + x.w*x.w;
  float tot = block_sum256(ss, buf);
  float sc = rsqrtf(tot * (1.f / (float)D) + 1e-6f);
  f4v wv = LD4(ln2 + idx);
  f4v h;
  h.x = x.x*sc*wv.x; h.y = x.y*sc*wv.y; h.z = x.z*sc*wv.z; h.w = x.w*sc*wv.w;
  *(f4v*)(h2 + b * D + idx) = h;
  float r0 = h.x * rw[idx * 2]     + h.y * rw[(idx + 1) * 2] +
             h.z * rw[(idx + 2) * 2] + h.w * rw[(idx + 3) * 2];
  float r1 = h.x * rw[idx * 2 + 1]     + h.y * rw[(idx + 1) * 2 + 1] +
             h.z * rw[(idx + 2) * 2 + 1] + h.w * rw[(idx + 3) * 2 + 1];
  r0 = block_sum256(r0, buf);
  r1 = block_sum256(r1, buf);
  if (threadIdx.x == 0) {
    float m = fmaxf(r0, r1);
    float e0 = __expf(r0 - m), e1 = __expf(r1 - m);
    float inv = 1.f / (e0 + e1);
    float p0 = e0 * inv, p1 = e1 * inv;
    topw[b] = fmaxf(p0, p1);
    sel[b] = (p1 > p0) ? 1 : 0;
  }
}

// K4: gate/up split-K partials, nt weight loads. grid=(14, KS5) = 448 blocks.
// Stores only tokens routed to this matrix's expert.
__global__ __launch_bounds__(256, 2) void k_gateup(const float* __restrict__ h2,
                                                   const float* __restrict__ gw,
                                                   const float* __restrict__ uw,
                                                   const int* __restrict__ sel,
                                                   float* __restrict__ Pgu) {
  __shared__ float xs[8 * CH5];
  __shared__ int ssel[8];
  int tid = threadIdx.x;
  int kc = blockIdx.y, colt = blockIdx.x;
  int i0 = kc * CH5;
  { int bb = tid >> 5, r = tid & 31;
    xs[tid] = h2[bb * D + i0 + r]; }
  if (tid < 8) ssel[tid] = sel[tid];
  __syncthreads();
  int c = colt * 1024 + tid * 4;     // flattened col over 4 matrices (4*F)
  int m = c / F;
  int j = c - m * F;
  const float* base = (m < 2 ? gw : uw) + (size_t)(m & 1) * D * F;
  const f4v* Wp = (const f4v*)(base + (size_t)i0 * F + j);
  const int st = F / 4;
  f4v acc0 = {0,0,0,0}, acc1 = {0,0,0,0}, acc2 = {0,0,0,0}, acc3 = {0,0,0,0};
  f4v acc4 = {0,0,0,0}, acc5 = {0,0,0,0}, acc6 = {0,0,0,0}, acc7 = {0,0,0,0};
  f4v w0 = wld<1>(Wp+0*st), w1 = wld<1>(Wp+1*st), w2 = wld<1>(Wp+2*st), w3 = wld<1>(Wp+3*st);
  f4v w4 = wld<1>(Wp+4*st), w5 = wld<1>(Wp+5*st), w6 = wld<1>(Wp+6*st), w7 = wld<1>(Wp+7*st);
  Wp += 8 * st;
  #pragma unroll
  for (int t = 0; t < CH5 / 8 - 1; t++) {
    f4v n0 = wld<1>(Wp+0*st), n1 = wld<1>(Wp+1*st), n2 = wld<1>(Wp+2*st), n3 = wld<1>(Wp+3*st);
    f4v n4 = wld<1>(Wp+4*st), n5 = wld<1>(Wp+5*st), n6 = wld<1>(Wp+6*st), n7 = wld<1>(Wp+7*st);
    Wp += 8 * st;
    ALL8(xs, CH5, t * 8);
    w0 = n0; w1 = n1; w2 = n2; w3 = n3; w4 = n4; w5 = n5; w6 = n6; w7 = n7;
  }
  ALL8(xs, CH5, CH5 - 8);
  int me = m & 1;
  #define GU_ST(bb, ACC) \
    if (ssel[bb] == me) \
      *(f4v*)(Pgu + (((size_t)kc * 4 + m) * 8 + (bb)) * F + j) = ACC;
  GU_ST(0, acc0) GU_ST(1, acc1) GU_ST(2, acc2) GU_ST(3, acc3)
  GU_ST(4, acc4) GU_ST(5, acc5) GU_ST(6, acc6) GU_ST(7, acc7)
  #undef GU_ST
}

// K5: silu-reduce Pgu slice -> LDS (selected tokens only), then down partials.
// grid = 2*KS6 = 448. Stores predicated.
__global__ __launch_bounds__(256, 2) void k_down(const float* __restrict__ Pgu,
                                                 const float* __restrict__ dw,
                                                 const int* __restrict__ sel,
                                                 float* __restrict__ Dp) {
  __shared__ float xs[8 * CH6];
  __shared__ int ssel[8];
  int tid = threadIdx.x;
  int e = blockIdx.x & 1, ch = blockIdx.x >> 1, i0 = ch * CH6;
  if (tid < 8) ssel[tid] = sel[tid];
  __syncthreads();
  if (tid < 128) {
    int bb = tid >> 4, ii = tid & 15;
    float r = 0.f;
    if (ssel[bb] == e) {
      float ga = 0.f, ua = 0.f;
      #pragma unroll
      for (int kc = 0; kc < KS5; kc++) {
        ga += Pgu[(((size_t)kc * 4 + e)     * 8 + bb) * F + i0 + ii];
        ua += Pgu[(((size_t)kc * 4 + 2 + e) * 8 + bb) * F + i0 + ii];
      }
      r = (ga / (1.f + __expf(-ga))) * ua;
    }
    xs[bb * CH6 + ii] = r;
  }
  __syncthreads();
  mv16<1>(dw + (size_t)e * F * D + (size_t)i0 * D, tid * 4,
          Dp + (((size_t)ch * 2 + e) * 8) * D, xs, ssel, e);
}

// K6 (NEW): Dp reduction at 64-block parallelism. Block (bb, q) reduces the
// 224 partials for token bb over column slice [q*128, q*128+128), adds the
// residual, stores x2 and a per-slice partial sumsq.
// Fixes the round-7 hidden cost: old k_final read 7.3 MB with 8 blocks.
__global__ __launch_bounds__(256, 2) void k_dred(const float* __restrict__ xr,
                                                 const float* __restrict__ Dp,
                                                 const float* __restrict__ topw,
                                                 const int* __restrict__ sel,
                                                 float* __restrict__ x2,
                                                 float* __restrict__ psq) {
  __shared__ f4v sh[8][32];
  int bb = blockIdx.x >> 3, q = blockIdx.x & 7;
  int e = sel[bb];
  float tw = topw[bb];
  int t = threadIdx.x;
  int c = t & 31, g = t >> 5;            // col f4 within slice, chunk-group
  int col = q * 128 + c * 4;
  f4v acc = {0,0,0,0};
  #pragma unroll 7
  for (int ch = g * 28; ch < g * 28 + 28; ch++)
    acc += LD4(Dp + (((size_t)ch * 2 + e) * 8 + bb) * D + col);
  sh[g][c] = acc;
  __syncthreads();
  if (t < 32) {
    f4v y = sh[0][t];
    #pragma unroll
    for (int gg = 1; gg < 8; gg++) y += sh[gg][t];
    int colt = q * 128 + t * 4;
    f4v x = LD4(xr + bb * D + colt);
    x += tw * y;
    *(f4v*)(x2 + bb * D + colt) = x;
    float ss = x.x*x.x + x.y*x.y + x.z*x.z + x.w*x.w;
    #pragma unroll
    for (int o = 16; o; o >>= 1) ss += __shfl_down(ss, o, 32);
    if (t == 0) psq[blockIdx.x] = ss;    // blockIdx.x == bb*8 + q
  }
}

// K7: final rmsnorm + score head, tiny reads only. grid=8.
__global__ void k_final(const float* __restrict__ x2, const float* __restrict__ psq,
                        const float* __restrict__ flw, const float* __restrict__ sw,
                        float* __restrict__ out) {
  __shared__ float buf[4];
  int b = blockIdx.x;
  float tot = 0.f;
  #pragma unroll
  for (int q = 0; q < 8; q++) tot += psq[b * 8 + q];
  float sc = rsqrtf(tot * (1.f / (float)D) + 1e-6f);
  int idx = threadIdx.x * 4;
  f4v x = LD4(x2 + b * D + idx);
  f4v wv = LD4(flw + idx);
  float n0 = x.x*sc*wv.x, n1 = x.y*sc*wv.y, n2 = x.z*sc*wv.z, n3 = x.w*sc*wv.w;
  float l0 = n0 * sw[idx * 2]     + n1 * sw[(idx + 1) * 2] +
             n2 * sw[(idx + 2) * 2] + n3 * sw[(idx + 3) * 2];
  float l1 = n0 * sw[idx * 2 + 1]     + n1 * sw[(idx + 1) * 2 + 1] +
             n2 * sw[(idx + 2) * 2 + 1] + n3 * sw[(idx + 3) * 2 + 1];
  l0 = block_sum256(l0, buf);
  l1 = block_sum256(l1, buf);
  if (threadIdx.x == 0) { out[b * 2 + 0] = l0; out[b * 2 + 1] = l1; }
}

extern "C" void kernel_launch(void* const* d_in, const int* in_sizes, int n_in,
                              void* d_out, int out_size, void* d_ws, size_t ws_size,
                              hipStream_t stream) {
  const float* hs  = (const float*)d_in[0];
  const float* ln1 = (const float*)d_in[1];
  // d_in[2]=q_w, d_in[3]=k_w: dead — token-0 causal attention only needs V.
  const float* vw  = (const float*)d_in[4];
  const float* ow  = (const float*)d_in[5];
  const float* ln2 = (const float*)d_in[6];
  const float* rw  = (const float*)d_in[7];
  const float* gw  = (const float*)d_in[8];
  const float* uw  = (const float*)d_in[9];
  const float* dw  = (const float*)d_in[10];
  const float* flw = (const float*)d_in[11];
  const float* sw  = (const float*)d_in[12];

  float* ws = (float*)d_ws;
  float* Vp   = ws;                     // 524288  (KSV*8*D)
  float* Op   = ws + 524288;            // 524288
  float* xr   = ws + 1048576;           // 8192
  float* h2   = ws + 1056768;           // 8192
  float* tw8  = ws + 1064960;           // 8
  int*   sel8 = (int*)(ws + 1064968);   // 8 (+pad to 128B line)
  float* Pgu  = ws + 1064992;           // KS5*4*8*F = 3670016 (128B-aligned)
  float* Dp   = ws + 4735008;           // KS6*2*8*D = 3670016 (128B-aligned)
  float* x2   = ws + 8405024;           // 8192
  float* psq  = ws + 8413216;           // 64
  // no atomics, no barrier -> no zero-init; every read cell is written first.

  k_mvp_v<<<KSV, 256, 0, stream>>>(hs, ln1, vw, Vp);
  k_ored<<<KSV, 256, 0, stream>>>(Vp, ow, Op);
  k_mid<<<8, 256, 0, stream>>>(hs, Op, ln2, rw, xr, h2, tw8, sel8);
  k_gateup<<<dim3(14, KS5), 256, 0, stream>>>(h2, gw, uw, sel8, Pgu);
  k_down<<<2 * KS6, 256, 0, stream>>>(Pgu, dw, sel8, Dp);
  k_dred<<<64, 256, 0, stream>>>(xr, Dp, tw8, sel8, x2, psq);
  k_final<<<8, 256, 0, stream>>>(x2, psq, flw, sw, (float*)d_out);
}